// Round 17
// baseline (285.163 us; speedup 1.0000x reference)
//
#include <hip/hip_runtime.h>

#define MT 4096      // tokens
#define DM 64        // d_model
#define NHEAD 8
#define HDIM 8
#define DFF 256
#define NLAYER 4
#define LN_EPS 1e-5f
#define ZSPLIT 4

// Q pre-scale: 1/sqrt(8) * log2(e)  (scores arrive in log2 domain -> v_exp_f32 direct)
#define QSCALE 0.51011784f
// -0.5 * log2(e) for the MMD gaussian
#define MMDC (-0.72134752f)

#if __has_builtin(__builtin_amdgcn_exp2f)
#define EXP2(x) __builtin_amdgcn_exp2f(x)
#else
#define EXP2(x) exp2f(x)
#endif

typedef __attribute__((ext_vector_type(8))) short bf16x8;
typedef __attribute__((ext_vector_type(4))) short bf16x4;
typedef __attribute__((ext_vector_type(4))) float f32x4;
typedef __attribute__((ext_vector_type(16))) float f32x16;
typedef __attribute__((ext_vector_type(4))) _Float16 f16x4;

__device__ __forceinline__ float wave_sum64(float v) {
#pragma unroll
  for (int m = 1; m < 64; m <<= 1) v += __shfl_xor(v, m, 64);
  return v;
}

__device__ __forceinline__ short f2bf(float x) {   // RNE float->bf16
  union { float f; unsigned u; } v; v.f = x;
  unsigned r = v.u + 0x7fffu + ((v.u >> 16) & 1u);
  return (short)(r >> 16);
}

__device__ __forceinline__ float bf2f(short s) {   // bf16 bits -> float
  union { float f; unsigned u; } v;
  v.u = ((unsigned)(unsigned short)s) << 16;
  return v.f;
}

// dword = [bf16trunc(b) : bf16trunc(a)]  (a -> low16) via one v_perm_b32
__device__ __forceinline__ unsigned packbf2(float a, float b) {
  union { float f; unsigned u; } x, y; x.f = a; y.f = b;
  return __builtin_amdgcn_perm(y.u, x.u, 0x07060302u);
}

// ---------------------------------------------------------------- prep: weight k4-pack + rgb prep + layer-0 qkv
__global__ __launch_bounds__(256) void prep_kernel(
    const float* __restrict__ inw, float* __restrict__ Wti,
    const float* __restrict__ ow,  float* __restrict__ Wto,
    const float* __restrict__ l1w, float* __restrict__ Wt1,
    const float* __restrict__ l2w, float* __restrict__ Wt2,
    const float* __restrict__ rgb, short* __restrict__ rgbb, float* __restrict__ nrm,
    const float* __restrict__ hsi, const float* __restrict__ inb, float* __restrict__ x,
    _Float16* __restrict__ Qh, _Float16* __restrict__ Kh, short* __restrict__ Vtb) {
  const int bid = blockIdx.x;
  const int tid = threadIdx.x;
  if (bid >= 1216) {
    // layer-0 qkv from hsi (+ x copy); weights read raw row-major (no race with packers)
    const int t0 = (bid - 1216) * 4;
    __shared__ float xr[4][DM];
    if (tid < 64) {
      float4 v = ((const float4*)(hsi + (size_t)t0 * DM))[tid];
      ((float4*)xr)[tid] = v;
      ((float4*)(x + (size_t)t0 * DM))[tid] = v;
    }
    __syncthreads();
    const int o = tid;
    if (o < 192) {
      float acc0 = inb[o], acc1 = acc0, acc2 = acc0, acc3 = acc0;
      const float* wrow = inw + (size_t)o * DM;
#pragma unroll 8
      for (int k4 = 0; k4 < 16; ++k4) {
        float4 w4 = *(const float4*)&wrow[k4 * 4];
        float4 a = *(const float4*)&xr[0][k4 * 4];
        acc0 += a.x * w4.x + a.y * w4.y + a.z * w4.z + a.w * w4.w;
        float4 b = *(const float4*)&xr[1][k4 * 4];
        acc1 += b.x * w4.x + b.y * w4.y + b.z * w4.z + b.w * w4.w;
        float4 c = *(const float4*)&xr[2][k4 * 4];
        acc2 += c.x * w4.x + c.y * w4.y + c.z * w4.z + c.w * w4.w;
        float4 d = *(const float4*)&xr[3][k4 * 4];
        acc3 += d.x * w4.x + d.y * w4.y + d.z * w4.z + d.w * w4.w;
      }
      if (o < 128) {
        const int c = o & 63, hh = c >> 3, ch = c & 7;
        _Float16* dst = (o < 64) ? Qh : Kh;
        const float sc = (o < 64) ? QSCALE : 1.0f;
        dst[((size_t)hh * MT + t0 + 0) * 8 + ch] = (_Float16)(acc0 * sc);
        dst[((size_t)hh * MT + t0 + 1) * 8 + ch] = (_Float16)(acc1 * sc);
        dst[((size_t)hh * MT + t0 + 2) * 8 + ch] = (_Float16)(acc2 * sc);
        dst[((size_t)hh * MT + t0 + 3) * 8 + ch] = (_Float16)(acc3 * sc);
      } else {
        const int c = o - 128;
        bf16x4 v = {f2bf(acc0), f2bf(acc1), f2bf(acc2), f2bf(acc3)};
        *(bf16x4*)&Vtb[(size_t)c * MT + t0] = v;
      }
    }
    return;
  }
  if (bid >= 192) {
    const int row = (bid - 192) * 4 + (tid >> 6);
    const int d = tid & 63;
    float v = rgb[(size_t)row * DM + d];
    rgbb[(size_t)row * DM + d] = f2bf(v);
    float s = wave_sum64(v * v);
    if (d == 0) nrm[MT + row] = s;
    return;
  }
  const float* src; float* dst; int R, C, r0, c0;
  if (bid < 48) {
    int l = bid / 12, t = bid % 12;
    src = inw + (size_t)l * 12288; dst = Wti + (size_t)l * 12288;
    R = 192; C = 64; c0 = (t % 2) * 32; r0 = (t / 2) * 32;
  } else if (bid < 64) {
    int idx = bid - 48, l = idx / 4, t = idx % 4;
    src = ow + (size_t)l * 4096; dst = Wto + (size_t)l * 4096;
    R = 64; C = 64; c0 = (t % 2) * 32; r0 = (t / 2) * 32;
  } else if (bid < 128) {
    int idx = bid - 64, l = idx / 16, t = idx % 16;
    src = l1w + (size_t)l * 16384; dst = Wt1 + (size_t)l * 16384;
    R = 256; C = 64; c0 = (t % 2) * 32; r0 = (t / 2) * 32;
  } else {
    int idx = bid - 128, l = idx / 16, t = idx % 16;
    src = l2w + (size_t)l * 16384; dst = Wt2 + (size_t)l * 16384;
    R = 64; C = 256; c0 = (t % 8) * 32; r0 = (t / 8) * 32;
  }
  __shared__ float tl[32][33];
  const int tx = tid & 31, ty = tid >> 5;
  for (int rr = ty; rr < 32; rr += 8)
    tl[rr][tx] = src[(size_t)(r0 + rr) * C + c0 + tx];
  __syncthreads();
  for (int idx = tid; idx < 1024; idx += 256) {
    const int k4l = idx >> 7, rem = idx & 127, ol = rem >> 2, j = rem & 3;
    dst[(((size_t)(c0 >> 2) + k4l) * R + r0 + ol) * 4 + j] = tl[ol][k4l * 4 + j];
  }
}

// ---------------------------------------------------------------- MFMA flash attention
// QK via 32x32x8 f16. 128-thread blocks (2 waves x 32 queries), z=4, grid
// (64,8,4)=2048 blocks; ~14KB LDS -> 11 blocks/CU co-resident, grid needs 8/CU
// -> ENTIRE grid resident, zero tail. (256->128 thr keeps inner loop identical.)
__global__ __launch_bounds__(128, 6) void attn_kernel(const _Float16* __restrict__ Qh,
                                                      const _Float16* __restrict__ Kh,
                                                      const short* __restrict__ Vtb,
                                                      short* __restrict__ pbufb,
                                                      float* __restrict__ lbuf) {
  const int h = blockIdx.y;
  const int qbase = blockIdx.x * 64;
  const int z = blockIdx.z;
  const int tid = threadIdx.x;
  const int wid = tid >> 6;
  const int lane = tid & 63;
  const int l31 = lane & 31;
  const int hi = lane >> 5;
  const int n = lane & 15;
  const int quad = lane >> 4;

  __shared__ short Klds[2][128 * 8];     // f16 bits [key][ch]
  __shared__ short Vtlds[2][9 * 136];    // bf16 [ch][key] + ones row 8, stride 136
  __shared__ short Plds[2][32 * 40];     // bf16 P^T [query][key32], stride 40

  if (tid < 32) {
    bf16x8 ones = {0x3F80, 0x3F80, 0x3F80, 0x3F80, 0x3F80, 0x3F80, 0x3F80, 0x3F80};
    *(bf16x8*)&Vtlds[tid >> 4][8 * 136 + (tid & 15) * 8] = ones;
  }

  const f16x4 qb = *(const f16x4*)&Qh[((size_t)h * MT + qbase + wid * 32 + l31) * 8 + hi * 4];
  const bf16x8 zero8 = {0, 0, 0, 0, 0, 0, 0, 0};

  // stage tile 0: every thread writes one K row AND one V^T segment
  {
    const int k0 = z * 1024;
    *(bf16x8*)&Klds[0][tid * 8] = *(const bf16x8*)&Kh[((size_t)h * MT + k0 + tid) * 8];
    const int ch = tid >> 4, seg = tid & 15;
    *(bf16x8*)&Vtlds[0][ch * 136 + seg * 8] =
        *(const bf16x8*)&Vtb[((size_t)h * 8 + ch) * MT + k0 + seg * 8];
  }
  __syncthreads();

  f32x4 o_acc0 = {0.f, 0.f, 0.f, 0.f};
  f32x4 o_acc1 = {0.f, 0.f, 0.f, 0.f};

  for (int kt = 0; kt < 8; ++kt) {
    const int buf = kt & 1;
    if (kt < 7) {
      const int k1 = z * 1024 + (kt + 1) * 128;
      *(bf16x8*)&Klds[buf ^ 1][tid * 8] = *(const bf16x8*)&Kh[((size_t)h * MT + k1 + tid) * 8];
      const int ch = tid >> 4, seg = tid & 15;
      *(bf16x8*)&Vtlds[buf ^ 1][ch * 136 + seg * 8] =
          *(const bf16x8*)&Vtb[((size_t)h * 8 + ch) * MT + k1 + seg * 8];
    }

#pragma unroll
    for (int c32 = 0; c32 < 4; ++c32) {
      // S^T(32k x 32q) = K(32x8) . Q^T(8x32)
      f16x4 ka = *(const f16x4*)&((const _Float16*)Klds[buf])[(c32 * 32 + l31) * 8 + hi * 4];
      f32x16 zf = {0.f, 0.f, 0.f, 0.f, 0.f, 0.f, 0.f, 0.f,
                   0.f, 0.f, 0.f, 0.f, 0.f, 0.f, 0.f, 0.f};
      f32x16 s = __builtin_amdgcn_mfma_f32_32x32x8f16(ka, qb, zf, 0, 0, 0);
      // lane: query=l31; reg r -> key (within chunk) = (r&3) + 8*(r>>2) + 4*hi
      short* pw = &Plds[wid][l31 * 40 + 4 * hi];
#pragma unroll
      for (int rg = 0; rg < 4; ++rg) {
        unsigned lo = packbf2(EXP2(s[4 * rg + 0]), EXP2(s[4 * rg + 1]));
        unsigned hi2 = packbf2(EXP2(s[4 * rg + 2]), EXP2(s[4 * rg + 3]));
        uint2 pv = {lo, hi2};
        *(uint2*)(pw + rg * 8) = pv;
      }
      // PV for this 32-key chunk (same wave wrote it; lgkmcnt ordering suffices)
      bf16x8 va = zero8;
      if (n < 9) va = *(const bf16x8*)&Vtlds[buf][n * 136 + c32 * 32 + quad * 8];
      bf16x8 p0 = *(const bf16x8*)&Plds[wid][n * 40 + quad * 8];
      o_acc0 = __builtin_amdgcn_mfma_f32_16x16x32_bf16(va, p0, o_acc0, 0, 0, 0);
      bf16x8 p1 = *(const bf16x8*)&Plds[wid][(n + 16) * 40 + quad * 8];
      o_acc1 = __builtin_amdgcn_mfma_f32_16x16x32_bf16(va, p1, o_acc1, 0, 0, 0);
    }
    __syncthreads();
  }

  const int tok0 = qbase + wid * 32 + n;
  if (quad < 2) {
    bf16x4 v0 = {f2bf(o_acc0[0]), f2bf(o_acc0[1]), f2bf(o_acc0[2]), f2bf(o_acc0[3])};
    *(bf16x4*)&pbufb[((size_t)z * MT + tok0) * DM + h * 8 + quad * 4] = v0;
    bf16x4 v1 = {f2bf(o_acc1[0]), f2bf(o_acc1[1]), f2bf(o_acc1[2]), f2bf(o_acc1[3])};
    *(bf16x4*)&pbufb[((size_t)z * MT + tok0 + 16) * DM + h * 8 + quad * 4] = v1;
  }
  if (quad == 2) {
    lbuf[(size_t)z * MT * 8 + (size_t)tok0 * 8 + h] = o_acc0[0];
    lbuf[(size_t)z * MT * 8 + (size_t)(tok0 + 16) * 8 + h] = o_acc1[0];
  }
}

// ---------------------------------------------------------------- fused dense layer (round-13/15 config)
// 512 threads = 8 waves; wave w -> token t0+w for oproj/ff2/LN phases;
// ff1/qkv use 2 groups x 256 threads (4 tokens each). 16 waves/CU.
__global__ __launch_bounds__(512) void dense_kernel(
    const short* __restrict__ pbufb, const float* __restrict__ lbuf,
    float* __restrict__ x,
    const float* __restrict__ Wto, const float* __restrict__ ob,
    const float* __restrict__ n1w, const float* __restrict__ n1b,
    const float* __restrict__ Wt1, const float* __restrict__ b1,
    const float* __restrict__ Wt2, const float* __restrict__ b2,
    const float* __restrict__ n2w, const float* __restrict__ n2b,
    const float* __restrict__ Wti, const float* __restrict__ inb,
    _Float16* __restrict__ Qh, _Float16* __restrict__ Kh, short* __restrict__ Vtb,
    int do_qkv,
    const float* __restrict__ mask, float* __restrict__ out,
    short* __restrict__ xmb, float* __restrict__ nrm, int do_final) {
  const int t0 = blockIdx.x * 8;
  const int tid = threadIdx.x;
  const int w = tid >> 6, d = tid & 63;

  __shared__ float orow[8][DM];
  __shared__ float x1[8][DM];
  __shared__ float fr[8][DFF];
  __shared__ float x2s[8][DM];

  // combine: wave w -> token t0+w (bf16 partials, fp32 l)
  {
    const int tok = t0 + w, h = d >> 3;
    float o = 0.f, l = 0.f;
#pragma unroll
    for (int z = 0; z < ZSPLIT; ++z) {
      o += bf2f(pbufb[((size_t)z * MT + tok) * DM + d]);
      l += lbuf[(size_t)z * MT * 8 + (size_t)tok * 8 + h];
    }
    orow[w][d] = o / l;
  }
  __syncthreads();

  // o-proj + residual + LN1: wave w -> token t0+w
  {
    const int tok = t0 + w;
    float acc = ob[d];
#pragma unroll 8
    for (int k4 = 0; k4 < 16; ++k4) {
      float4 w4 = ((const float4*)Wto)[k4 * 64 + d];
      float4 a = *(const float4*)&orow[w][k4 * 4];
      acc += a.x * w4.x + a.y * w4.y + a.z * w4.z + a.w * w4.w;
    }
    float hv = x[(size_t)tok * DM + d] + acc;
    float mu = wave_sum64(hv) * (1.0f / DM);
    float dv = hv - mu;
    float var = wave_sum64(dv * dv) * (1.0f / DM);
    x1[w][d] = dv * rsqrtf(var + LN_EPS) * n1w[d] + n1b[d];
  }
  __syncthreads();

  // ff1: group g = tid>>8 handles tokens g*4..g*4+3, thread output o = tid&255
  {
    const int g = tid >> 8, o = tid & 255;
    float acc[4];
#pragma unroll
    for (int t = 0; t < 4; ++t) acc[t] = b1[o];
#pragma unroll 8
    for (int k4 = 0; k4 < 16; ++k4) {
      float4 w4 = ((const float4*)Wt1)[k4 * 256 + o];
#pragma unroll
      for (int t = 0; t < 4; ++t) {
        float4 a = *(const float4*)&x1[g * 4 + t][k4 * 4];
        acc[t] += a.x * w4.x + a.y * w4.y + a.z * w4.z + a.w * w4.w;
      }
    }
#pragma unroll
    for (int t = 0; t < 4; ++t) fr[g * 4 + t][o] = fmaxf(acc[t], 0.0f);
  }
  __syncthreads();

  // ff2 + residual + LN2 (+ final): wave w -> token t0+w
  {
    const int tok = t0 + w;
    float acc = b2[d];
#pragma unroll 8
    for (int k4 = 0; k4 < 64; ++k4) {
      float4 w4 = ((const float4*)Wt2)[k4 * 64 + d];
      float4 a = *(const float4*)&fr[w][k4 * 4];
      acc += a.x * w4.x + a.y * w4.y + a.z * w4.z + a.w * w4.w;
    }
    float hv = x1[w][d] + acc;
    float mu = wave_sum64(hv) * (1.0f / DM);
    float dv = hv - mu;
    float var = wave_sum64(dv * dv) * (1.0f / DM);
    float v = dv * rsqrtf(var + LN_EPS) * n2w[d] + n2b[d];
    x2s[w][d] = v;
    x[(size_t)tok * DM + d] = v;
    if (do_final) {
      float pv = v * mask[d];
      out[(size_t)tok * DM + d] = pv;
      xmb[(size_t)tok * DM + d] = f2bf(pv);
      float s = wave_sum64(pv * pv);
      if (d == 0) nrm[tok] = s;
    }
  }
  __syncthreads();

  // qkv for next layer: group g, thread output o (192 used per group)
  if (do_qkv) {
    const int g = tid >> 8, o = tid & 255;
    if (o < 192) {
      float acc[4];
#pragma unroll
      for (int t = 0; t < 4; ++t) acc[t] = inb[o];
#pragma unroll 8
      for (int k4 = 0; k4 < 16; ++k4) {
        float4 w4 = ((const float4*)Wti)[k4 * 192 + o];
#pragma unroll
        for (int t = 0; t < 4; ++t) {
          float4 a = *(const float4*)&x2s[g * 4 + t][k4 * 4];
          acc[t] += a.x * w4.x + a.y * w4.y + a.z * w4.z + a.w * w4.w;
        }
      }
      if (o < 128) {
        const int c = o & 63, hh = c >> 3, ch = c & 7;
        _Float16* dst = (o < 64) ? Qh : Kh;
        const float sc = (o < 64) ? QSCALE : 1.0f;
#pragma unroll
        for (int t = 0; t < 4; ++t)
          dst[((size_t)hh * MT + t0 + g * 4 + t) * 8 + ch] = (_Float16)(acc[t] * sc);
      } else {
        bf16x4 v = {f2bf(acc[0]), f2bf(acc[1]), f2bf(acc[2]), f2bf(acc[3])};
        *(bf16x4*)&Vtb[(size_t)(o - 128) * MT + t0 + g * 4] = v;
      }
    }
  }
}

// ---------------------------------------------------------------- MMD via MFMA, symmetric-triangle grid
__global__ __launch_bounds__(256) void mmd_kernel(const short* __restrict__ xmb,
                                                  const short* __restrict__ rgbb,
                                                  const float* __restrict__ nrm,
                                                  float* __restrict__ partials) {
  const int bid = blockIdx.x;
  int p, bx, by;
  float coef;
  if (bid < 1024) {
    p = 2; bx = bid & 31; by = bid >> 5; coef = -2.0f;
  } else {
    const int t = bid - 1024;
    p = (t < 528) ? 0 : 1;
    const int u = (t < 528) ? t : t - 528;
    by = (int)((sqrtf(8.0f * (float)u + 1.0f) - 1.0f) * 0.5f);
    while ((by + 1) * (by + 2) / 2 <= u) ++by;
    while (by * (by + 1) / 2 > u) --by;
    bx = u - by * (by + 1) / 2;
    coef = (bx == by) ? 1.0f : 2.0f;
  }
  const short* A = (p == 1) ? rgbb : xmb;
  const short* B = (p == 0) ? xmb : rgbb;
  const float* nA = (p == 1) ? (nrm + MT) : nrm;
  const float* nB = (p == 0) ? nrm : (nrm + MT);
  const int i0 = bx * 128;
  const int j0 = by * 128;
  const int tid = threadIdx.x;
  const int wid = tid >> 6;
  const int lane = tid & 63;
  const int n = lane & 15;
  const int quad = lane >> 4;

  bf16x8 a0[2], a1[2];
  float na[2][4];
#pragma unroll
  for (int s = 0; s < 2; ++s) {
    const int arow = i0 + wid * 32 + s * 16 + n;
    a0[s] = *(const bf16x8*)&A[(size_t)arow * DM + quad * 8];
    a1[s] = *(const bf16x8*)&A[(size_t)arow * DM + 32 + quad * 8];
#pragma unroll
    for (int r = 0; r < 4; ++r) na[s][r] = nA[i0 + wid * 32 + s * 16 + quad * 4 + r];
  }
  bf16x8 b0[8], b1[8];
  float nb[8];
#pragma unroll
  for (int nt = 0; nt < 8; ++nt) {
    const int brow = j0 + nt * 16 + n;
    b0[nt] = *(const bf16x8*)&B[(size_t)brow * DM + quad * 8];
    b1[nt] = *(const bf16x8*)&B[(size_t)brow * DM + 32 + quad * 8];
    nb[nt] = nB[j0 + nt * 16 + n];
  }

  float local = 0.f;
#pragma unroll
  for (int nt = 0; nt < 8; ++nt) {
#pragma unroll
    for (int s = 0; s < 2; ++s) {
      f32x4 zf = {0.f, 0.f, 0.f, 0.f};
      f32x4 d4 = __builtin_amdgcn_mfma_f32_16x16x32_bf16(a0[s], b0[nt], zf, 0, 0, 0);
      d4 = __builtin_amdgcn_mfma_f32_16x16x32_bf16(a1[s], b1[nt], d4, 0, 0, 0);
#pragma unroll
      for (int r = 0; r < 4; ++r) {
        float dist = na[s][r] + nb[nt] - 2.0f * d4[r];
        local += EXP2(MMDC * dist);
      }
    }
  }

  float tot = wave_sum64(local);
  __shared__ float wpart[4];
  if (lane == 0) wpart[wid] = tot;
  __syncthreads();
  if (tid == 0)
    partials[bid] = coef * (wpart[0] + wpart[1] + wpart[2] + wpart[3]);
}

// ---------------------------------------------------------------- reduce + finalize (1 block)
__global__ __launch_bounds__(256) void reducefin_kernel(const float* __restrict__ partials,
                                                        float* __restrict__ out) {
  const int tid = threadIdx.x;
  float s = 0.f;
  for (int i = tid; i < 2080; i += 256) s += partials[i];
  s = wave_sum64(s);
  __shared__ float L[4];
  if ((tid & 63) == 0) L[tid >> 6] = s;
  __syncthreads();
  if (tid == 0) {
    const float invn = 1.0f / ((float)MT * (float)MT);
    out[(size_t)MT * DM] = (L[0] + L[1] + L[2] + L[3]) * invn;
  }
}

// ================================================================ launcher
extern "C" void kernel_launch(void* const* d_in, const int* in_sizes, int n_in,
                              void* d_out, int out_size, void* d_ws, size_t ws_size,
                              hipStream_t stream) {
  const float* hsi  = (const float*)d_in[0];
  const float* rgb  = (const float*)d_in[1];
  const float* inw  = (const float*)d_in[2];
  const float* inb  = (const float*)d_in[3];
  const float* ow   = (const float*)d_in[4];
  const float* obv  = (const float*)d_in[5];
  const float* l1w  = (const float*)d_in[6];
  const float* l1b  = (const float*)d_in[7];
  const float* l2w  = (const float*)d_in[8];
  const float* l2b  = (const float*)d_in[9];
  const float* n1w  = (const float*)d_in[10];
  const float* n1b  = (const float*)d_in[11];
  const float* n2w  = (const float*)d_in[12];
  const float* n2b  = (const float*)d_in[13];
  const float* mask = (const float*)d_in[14];
  float* out = (float*)d_out;

  float* ws      = (float*)d_ws;
  float* x       = ws;                          // 262144
  short* pbufb   = (short*)(ws + 262144);       // 4 z * MT*64 shorts = 524288 floats
  float* lbuf    = ws + 786432;                 // 4 * 32768 = 131072
  float* nrm     = ws + 917504;                 // 8192
  float* parts   = ws + 925696;                 // 4096
  float* Wti     = ws + 929792;                 // 49152 (packed)
  float* Wto     = ws + 978944;                 // 16384
  float* Wt1     = ws + 995328;                 // 65536
  float* Wt2     = ws + 1060864;                // 65536
  short* xmb     = (short*)(ws + 1126400);      // 262144 shorts
  short* rgbb    = (short*)(ws + 1257472);      // 262144 shorts
  _Float16* Qh   = (_Float16*)(ws + 1388544);   // 262144 f16
  _Float16* Kh   = (_Float16*)(ws + 1519616);   // 262144 f16
  short* Vtb     = (short*)(ws + 1650688);      // 262144 shorts

  prep_kernel<<<192 + MT / 4 + MT / 4, 256, 0, stream>>>(
      inw, Wti, ow, Wto, l1w, Wt1, l2w, Wt2, rgb, rgbb, nrm,
      hsi, inb, x, Qh, Kh, Vtb);

  for (int i = 0; i < NLAYER; ++i) {
    attn_kernel<<<dim3(MT / 64, NHEAD, ZSPLIT), 128, 0, stream>>>(Qh, Kh, Vtb, pbufb, lbuf);
    const int last = (i == NLAYER - 1);
    dense_kernel<<<MT / 8, 512, 0, stream>>>(
        pbufb, lbuf, x,
        Wto + (size_t)i * DM * DM, obv + (size_t)i * DM,
        n1w + (size_t)i * DM, n1b + (size_t)i * DM,
        Wt1 + (size_t)i * DFF * DM, l1b + (size_t)i * DFF,
        Wt2 + (size_t)i * DM * DFF, l2b + (size_t)i * DM,
        n2w + (size_t)i * DM, n2b + (size_t)i * DM,
        Wti + (size_t)(last ? 0 : (i + 1)) * 192 * DM,
        inb + (size_t)(last ? 0 : (i + 1)) * 192,
        Qh, Kh, Vtb, !last,
        mask, out, xmb, nrm, last);
  }

  mmd_kernel<<<2080, 256, 0, stream>>>(xmb, rgbb, nrm, parts);
  reducefin_kernel<<<1, 256, 0, stream>>>(parts, out);
}

// Round 18
// 279.203 us; speedup vs baseline: 1.0213x; 1.0213x over previous
//
#include <hip/hip_runtime.h>

#define MT 4096      // tokens
#define DM 64        // d_model
#define NHEAD 8
#define HDIM 8
#define DFF 256
#define NLAYER 4
#define LN_EPS 1e-5f
#define ZSPLIT 8

// Q pre-scale: 1/sqrt(8) * log2(e)  (scores arrive in log2 domain -> v_exp_f32 direct)
#define QSCALE 0.51011784f
// -0.5 * log2(e) for the MMD gaussian
#define MMDC (-0.72134752f)

#if __has_builtin(__builtin_amdgcn_exp2f)
#define EXP2(x) __builtin_amdgcn_exp2f(x)
#else
#define EXP2(x) exp2f(x)
#endif

typedef __attribute__((ext_vector_type(8))) short bf16x8;
typedef __attribute__((ext_vector_type(4))) short bf16x4;
typedef __attribute__((ext_vector_type(4))) float f32x4;
typedef __attribute__((ext_vector_type(16))) float f32x16;
typedef __attribute__((ext_vector_type(4))) _Float16 f16x4;

__device__ __forceinline__ float wave_sum64(float v) {
#pragma unroll
  for (int m = 1; m < 64; m <<= 1) v += __shfl_xor(v, m, 64);
  return v;
}

__device__ __forceinline__ short f2bf(float x) {   // RNE float->bf16
  union { float f; unsigned u; } v; v.f = x;
  unsigned r = v.u + 0x7fffu + ((v.u >> 16) & 1u);
  return (short)(r >> 16);
}

__device__ __forceinline__ float bf2f(short s) {   // bf16 bits -> float
  union { float f; unsigned u; } v;
  v.u = ((unsigned)(unsigned short)s) << 16;
  return v.f;
}

// dword = [bf16trunc(b) : bf16trunc(a)]  (a -> low16) via one v_perm_b32
__device__ __forceinline__ unsigned packbf2(float a, float b) {
  union { float f; unsigned u; } x, y; x.f = a; y.f = b;
  return __builtin_amdgcn_perm(y.u, x.u, 0x07060302u);
}

// ---------------------------------------------------------------- prep: weight k4-pack + rgb prep + layer-0 qkv
__global__ __launch_bounds__(256) void prep_kernel(
    const float* __restrict__ inw, float* __restrict__ Wti,
    const float* __restrict__ ow,  float* __restrict__ Wto,
    const float* __restrict__ l1w, float* __restrict__ Wt1,
    const float* __restrict__ l2w, float* __restrict__ Wt2,
    const float* __restrict__ rgb, short* __restrict__ rgbb, float* __restrict__ nrm,
    const float* __restrict__ hsi, const float* __restrict__ inb, float* __restrict__ x,
    _Float16* __restrict__ Qh, _Float16* __restrict__ Kh, short* __restrict__ Vtb) {
  const int bid = blockIdx.x;
  const int tid = threadIdx.x;
  if (bid >= 1216) {
    // layer-0 qkv from hsi (+ x copy); weights read raw row-major (no race with packers)
    const int t0 = (bid - 1216) * 4;
    __shared__ float xr[4][DM];
    if (tid < 64) {
      float4 v = ((const float4*)(hsi + (size_t)t0 * DM))[tid];
      ((float4*)xr)[tid] = v;
      ((float4*)(x + (size_t)t0 * DM))[tid] = v;
    }
    __syncthreads();
    const int o = tid;
    if (o < 192) {
      float acc0 = inb[o], acc1 = acc0, acc2 = acc0, acc3 = acc0;
      const float* wrow = inw + (size_t)o * DM;
#pragma unroll 8
      for (int k4 = 0; k4 < 16; ++k4) {
        float4 w4 = *(const float4*)&wrow[k4 * 4];
        float4 a = *(const float4*)&xr[0][k4 * 4];
        acc0 += a.x * w4.x + a.y * w4.y + a.z * w4.z + a.w * w4.w;
        float4 b = *(const float4*)&xr[1][k4 * 4];
        acc1 += b.x * w4.x + b.y * w4.y + b.z * w4.z + b.w * w4.w;
        float4 c = *(const float4*)&xr[2][k4 * 4];
        acc2 += c.x * w4.x + c.y * w4.y + c.z * w4.z + c.w * w4.w;
        float4 d = *(const float4*)&xr[3][k4 * 4];
        acc3 += d.x * w4.x + d.y * w4.y + d.z * w4.z + d.w * w4.w;
      }
      if (o < 128) {
        const int c = o & 63, hh = c >> 3, ch = c & 7;
        _Float16* dst = (o < 64) ? Qh : Kh;
        const float sc = (o < 64) ? QSCALE : 1.0f;
        dst[((size_t)hh * MT + t0 + 0) * 8 + ch] = (_Float16)(acc0 * sc);
        dst[((size_t)hh * MT + t0 + 1) * 8 + ch] = (_Float16)(acc1 * sc);
        dst[((size_t)hh * MT + t0 + 2) * 8 + ch] = (_Float16)(acc2 * sc);
        dst[((size_t)hh * MT + t0 + 3) * 8 + ch] = (_Float16)(acc3 * sc);
      } else {
        const int c = o - 128;
        bf16x4 v = {f2bf(acc0), f2bf(acc1), f2bf(acc2), f2bf(acc3)};
        *(bf16x4*)&Vtb[(size_t)c * MT + t0] = v;
      }
    }
    return;
  }
  if (bid >= 192) {
    const int row = (bid - 192) * 4 + (tid >> 6);
    const int d = tid & 63;
    float v = rgb[(size_t)row * DM + d];
    rgbb[(size_t)row * DM + d] = f2bf(v);
    float s = wave_sum64(v * v);
    if (d == 0) nrm[MT + row] = s;
    return;
  }
  const float* src; float* dst; int R, C, r0, c0;
  if (bid < 48) {
    int l = bid / 12, t = bid % 12;
    src = inw + (size_t)l * 12288; dst = Wti + (size_t)l * 12288;
    R = 192; C = 64; c0 = (t % 2) * 32; r0 = (t / 2) * 32;
  } else if (bid < 64) {
    int idx = bid - 48, l = idx / 4, t = idx % 4;
    src = ow + (size_t)l * 4096; dst = Wto + (size_t)l * 4096;
    R = 64; C = 64; c0 = (t % 2) * 32; r0 = (t / 2) * 32;
  } else if (bid < 128) {
    int idx = bid - 64, l = idx / 16, t = idx % 16;
    src = l1w + (size_t)l * 16384; dst = Wt1 + (size_t)l * 16384;
    R = 256; C = 64; c0 = (t % 2) * 32; r0 = (t / 2) * 32;
  } else {
    int idx = bid - 128, l = idx / 16, t = idx % 16;
    src = l2w + (size_t)l * 16384; dst = Wt2 + (size_t)l * 16384;
    R = 64; C = 256; c0 = (t % 8) * 32; r0 = (t / 8) * 32;
  }
  __shared__ float tl[32][33];
  const int tx = tid & 31, ty = tid >> 5;
  for (int rr = ty; rr < 32; rr += 8)
    tl[rr][tx] = src[(size_t)(r0 + rr) * C + c0 + tx];
  __syncthreads();
  for (int idx = tid; idx < 1024; idx += 256) {
    const int k4l = idx >> 7, rem = idx & 127, ol = rem >> 2, j = rem & 3;
    dst[(((size_t)(c0 >> 2) + k4l) * R + r0 + ol) * 4 + j] = tl[ol][k4l * 4 + j];
  }
}

// ---------------------------------------------------------------- MFMA flash attention
// QK via 32x32x8 f16. Wave owns 32 queries. z=8 key split (512 keys/z) ->
// grid (32,8,8)=2048 blocks -> 6 blocks/CU (VGPR-capped) = 24 waves/CU.
// Partials stored bf16 (RNE) so z=8 costs the same pbuf bytes as fp32 z=4.
__global__ __launch_bounds__(256, 6) void attn_kernel(const _Float16* __restrict__ Qh,
                                                      const _Float16* __restrict__ Kh,
                                                      const short* __restrict__ Vtb,
                                                      short* __restrict__ pbufb,
                                                      float* __restrict__ lbuf) {
  const int h = blockIdx.y;
  const int qbase = blockIdx.x * 128;
  const int z = blockIdx.z;
  const int tid = threadIdx.x;
  const int wid = tid >> 6;
  const int lane = tid & 63;
  const int l31 = lane & 31;
  const int hi = lane >> 5;
  const int n = lane & 15;
  const int quad = lane >> 4;

  __shared__ short Klds[2][128 * 8];     // f16 bits [key][ch]
  __shared__ short Vtlds[2][9 * 136];    // bf16 [ch][key] + ones row 8, stride 136
  __shared__ short Plds[4][32 * 40];     // bf16 P^T [query][key32], stride 40

  if (tid < 32) {
    bf16x8 ones = {0x3F80, 0x3F80, 0x3F80, 0x3F80, 0x3F80, 0x3F80, 0x3F80, 0x3F80};
    *(bf16x8*)&Vtlds[tid >> 4][8 * 136 + (tid & 15) * 8] = ones;
  }

  const f16x4 qb = *(const f16x4*)&Qh[((size_t)h * MT + qbase + wid * 32 + l31) * 8 + hi * 4];
  const bf16x8 zero8 = {0, 0, 0, 0, 0, 0, 0, 0};

  {
    const int k0 = z * 512;
    if (tid < 128) {
      *(bf16x8*)&Klds[0][tid * 8] = *(const bf16x8*)&Kh[((size_t)h * MT + k0 + tid) * 8];
    } else {
      const int t2 = tid - 128, ch = t2 >> 4, seg = t2 & 15;
      *(bf16x8*)&Vtlds[0][ch * 136 + seg * 8] =
          *(const bf16x8*)&Vtb[((size_t)h * 8 + ch) * MT + k0 + seg * 8];
    }
  }
  __syncthreads();

  f32x4 o_acc0 = {0.f, 0.f, 0.f, 0.f};
  f32x4 o_acc1 = {0.f, 0.f, 0.f, 0.f};

  for (int kt = 0; kt < 4; ++kt) {
    const int buf = kt & 1;
    if (kt < 3) {
      const int k1 = z * 512 + (kt + 1) * 128;
      if (tid < 128) {
        *(bf16x8*)&Klds[buf ^ 1][tid * 8] = *(const bf16x8*)&Kh[((size_t)h * MT + k1 + tid) * 8];
      } else {
        const int t2 = tid - 128, ch = t2 >> 4, seg = t2 & 15;
        *(bf16x8*)&Vtlds[buf ^ 1][ch * 136 + seg * 8] =
            *(const bf16x8*)&Vtb[((size_t)h * 8 + ch) * MT + k1 + seg * 8];
      }
    }

#pragma unroll
    for (int c32 = 0; c32 < 4; ++c32) {
      // S^T(32k x 32q) = K(32x8) . Q^T(8x32)
      f16x4 ka = *(const f16x4*)&((const _Float16*)Klds[buf])[(c32 * 32 + l31) * 8 + hi * 4];
      f32x16 zf = {0.f, 0.f, 0.f, 0.f, 0.f, 0.f, 0.f, 0.f,
                   0.f, 0.f, 0.f, 0.f, 0.f, 0.f, 0.f, 0.f};
      f32x16 s = __builtin_amdgcn_mfma_f32_32x32x8f16(ka, qb, zf, 0, 0, 0);
      // lane: query=l31; reg r -> key (within chunk) = (r&3) + 8*(r>>2) + 4*hi
      short* pw = &Plds[wid][l31 * 40 + 4 * hi];
#pragma unroll
      for (int rg = 0; rg < 4; ++rg) {
        unsigned lo = packbf2(EXP2(s[4 * rg + 0]), EXP2(s[4 * rg + 1]));
        unsigned hi2 = packbf2(EXP2(s[4 * rg + 2]), EXP2(s[4 * rg + 3]));
        uint2 pv = {lo, hi2};
        *(uint2*)(pw + rg * 8) = pv;
      }
      // PV for this 32-key chunk (same wave wrote it; lgkmcnt ordering suffices)
      bf16x8 va = zero8;
      if (n < 9) va = *(const bf16x8*)&Vtlds[buf][n * 136 + c32 * 32 + quad * 8];
      bf16x8 p0 = *(const bf16x8*)&Plds[wid][n * 40 + quad * 8];
      o_acc0 = __builtin_amdgcn_mfma_f32_16x16x32_bf16(va, p0, o_acc0, 0, 0, 0);
      bf16x8 p1 = *(const bf16x8*)&Plds[wid][(n + 16) * 40 + quad * 8];
      o_acc1 = __builtin_amdgcn_mfma_f32_16x16x32_bf16(va, p1, o_acc1, 0, 0, 0);
    }
    __syncthreads();
  }

  const int tok0 = qbase + wid * 32 + n;
  if (quad < 2) {
    bf16x4 v0 = {f2bf(o_acc0[0]), f2bf(o_acc0[1]), f2bf(o_acc0[2]), f2bf(o_acc0[3])};
    *(bf16x4*)&pbufb[((size_t)z * MT + tok0) * DM + h * 8 + quad * 4] = v0;
    bf16x4 v1 = {f2bf(o_acc1[0]), f2bf(o_acc1[1]), f2bf(o_acc1[2]), f2bf(o_acc1[3])};
    *(bf16x4*)&pbufb[((size_t)z * MT + tok0 + 16) * DM + h * 8 + quad * 4] = v1;
  }
  if (quad == 2) {
    lbuf[(size_t)z * MT * 8 + (size_t)tok0 * 8 + h] = o_acc0[0];
    lbuf[(size_t)z * MT * 8 + (size_t)(tok0 + 16) * 8 + h] = o_acc1[0];
  }
}

// ---------------------------------------------------------------- fused dense layer
// 512 threads = 8 waves; wave w -> token t0+w for oproj/ff2/LN phases;
// ff1/qkv use 2 groups x 256 threads (4 tokens each). 16 waves/CU.
__global__ __launch_bounds__(512) void dense_kernel(
    const short* __restrict__ pbufb, const float* __restrict__ lbuf,
    float* __restrict__ x,
    const float* __restrict__ Wto, const float* __restrict__ ob,
    const float* __restrict__ n1w, const float* __restrict__ n1b,
    const float* __restrict__ Wt1, const float* __restrict__ b1,
    const float* __restrict__ Wt2, const float* __restrict__ b2,
    const float* __restrict__ n2w, const float* __restrict__ n2b,
    const float* __restrict__ Wti, const float* __restrict__ inb,
    _Float16* __restrict__ Qh, _Float16* __restrict__ Kh, short* __restrict__ Vtb,
    int do_qkv,
    const float* __restrict__ mask, float* __restrict__ out,
    short* __restrict__ xmb, float* __restrict__ nrm, int do_final) {
  const int t0 = blockIdx.x * 8;
  const int tid = threadIdx.x;
  const int w = tid >> 6, d = tid & 63;

  __shared__ float orow[8][DM];
  __shared__ float x1[8][DM];
  __shared__ float fr[8][DFF];
  __shared__ float x2s[8][DM];

  // combine: wave w -> token t0+w (bf16 partials, fp32 l)
  {
    const int tok = t0 + w, h = d >> 3;
    float o = 0.f, l = 0.f;
#pragma unroll
    for (int z = 0; z < ZSPLIT; ++z) {
      o += bf2f(pbufb[((size_t)z * MT + tok) * DM + d]);
      l += lbuf[(size_t)z * MT * 8 + (size_t)tok * 8 + h];
    }
    orow[w][d] = o / l;
  }
  __syncthreads();

  // o-proj + residual + LN1: wave w -> token t0+w
  {
    const int tok = t0 + w;
    float acc = ob[d];
#pragma unroll 8
    for (int k4 = 0; k4 < 16; ++k4) {
      float4 w4 = ((const float4*)Wto)[k4 * 64 + d];
      float4 a = *(const float4*)&orow[w][k4 * 4];
      acc += a.x * w4.x + a.y * w4.y + a.z * w4.z + a.w * w4.w;
    }
    float hv = x[(size_t)tok * DM + d] + acc;
    float mu = wave_sum64(hv) * (1.0f / DM);
    float dv = hv - mu;
    float var = wave_sum64(dv * dv) * (1.0f / DM);
    x1[w][d] = dv * rsqrtf(var + LN_EPS) * n1w[d] + n1b[d];
  }
  __syncthreads();

  // ff1: group g = tid>>8 handles tokens g*4..g*4+3, thread output o = tid&255
  {
    const int g = tid >> 8, o = tid & 255;
    float acc[4];
#pragma unroll
    for (int t = 0; t < 4; ++t) acc[t] = b1[o];
#pragma unroll 8
    for (int k4 = 0; k4 < 16; ++k4) {
      float4 w4 = ((const float4*)Wt1)[k4 * 256 + o];
#pragma unroll
      for (int t = 0; t < 4; ++t) {
        float4 a = *(const float4*)&x1[g * 4 + t][k4 * 4];
        acc[t] += a.x * w4.x + a.y * w4.y + a.z * w4.z + a.w * w4.w;
      }
    }
#pragma unroll
    for (int t = 0; t < 4; ++t) fr[g * 4 + t][o] = fmaxf(acc[t], 0.0f);
  }
  __syncthreads();

  // ff2 + residual + LN2 (+ final): wave w -> token t0+w
  {
    const int tok = t0 + w;
    float acc = b2[d];
#pragma unroll 8
    for (int k4 = 0; k4 < 64; ++k4) {
      float4 w4 = ((const float4*)Wt2)[k4 * 64 + d];
      float4 a = *(const float4*)&fr[w][k4 * 4];
      acc += a.x * w4.x + a.y * w4.y + a.z * w4.z + a.w * w4.w;
    }
    float hv = x1[w][d] + acc;
    float mu = wave_sum64(hv) * (1.0f / DM);
    float dv = hv - mu;
    float var = wave_sum64(dv * dv) * (1.0f / DM);
    float v = dv * rsqrtf(var + LN_EPS) * n2w[d] + n2b[d];
    x2s[w][d] = v;
    x[(size_t)tok * DM + d] = v;
    if (do_final) {
      float pv = v * mask[d];
      out[(size_t)tok * DM + d] = pv;
      xmb[(size_t)tok * DM + d] = f2bf(pv);
      float s = wave_sum64(pv * pv);
      if (d == 0) nrm[tok] = s;
    }
  }
  __syncthreads();

  // qkv for next layer: group g, thread output o (192 used per group)
  if (do_qkv) {
    const int g = tid >> 8, o = tid & 255;
    if (o < 192) {
      float acc[4];
#pragma unroll
      for (int t = 0; t < 4; ++t) acc[t] = inb[o];
#pragma unroll 8
      for (int k4 = 0; k4 < 16; ++k4) {
        float4 w4 = ((const float4*)Wti)[k4 * 192 + o];
#pragma unroll
        for (int t = 0; t < 4; ++t) {
          float4 a = *(const float4*)&x2s[g * 4 + t][k4 * 4];
          acc[t] += a.x * w4.x + a.y * w4.y + a.z * w4.z + a.w * w4.w;
        }
      }
      if (o < 128) {
        const int c = o & 63, hh = c >> 3, ch = c & 7;
        _Float16* dst = (o < 64) ? Qh : Kh;
        const float sc = (o < 64) ? QSCALE : 1.0f;
#pragma unroll
        for (int t = 0; t < 4; ++t)
          dst[((size_t)hh * MT + t0 + g * 4 + t) * 8 + ch] = (_Float16)(acc[t] * sc);
      } else {
        bf16x4 v = {f2bf(acc[0]), f2bf(acc[1]), f2bf(acc[2]), f2bf(acc[3])};
        *(bf16x4*)&Vtb[(size_t)(o - 128) * MT + t0 + g * 4] = v;
      }
    }
  }
}

// ---------------------------------------------------------------- MMD via MFMA, symmetric-triangle grid
__global__ __launch_bounds__(256) void mmd_kernel(const short* __restrict__ xmb,
                                                  const short* __restrict__ rgbb,
                                                  const float* __restrict__ nrm,
                                                  float* __restrict__ partials) {
  const int bid = blockIdx.x;
  int p, bx, by;
  float coef;
  if (bid < 1024) {
    p = 2; bx = bid & 31; by = bid >> 5; coef = -2.0f;
  } else {
    const int t = bid - 1024;
    p = (t < 528) ? 0 : 1;
    const int u = (t < 528) ? t : t - 528;
    by = (int)((sqrtf(8.0f * (float)u + 1.0f) - 1.0f) * 0.5f);
    while ((by + 1) * (by + 2) / 2 <= u) ++by;
    while (by * (by + 1) / 2 > u) --by;
    bx = u - by * (by + 1) / 2;
    coef = (bx == by) ? 1.0f : 2.0f;
  }
  const short* A = (p == 1) ? rgbb : xmb;
  const short* B = (p == 0) ? xmb : rgbb;
  const float* nA = (p == 1) ? (nrm + MT) : nrm;
  const float* nB = (p == 0) ? nrm : (nrm + MT);
  const int i0 = bx * 128;
  const int j0 = by * 128;
  const int tid = threadIdx.x;
  const int wid = tid >> 6;
  const int lane = tid & 63;
  const int n = lane & 15;
  const int quad = lane >> 4;

  bf16x8 a0[2], a1[2];
  float na[2][4];
#pragma unroll
  for (int s = 0; s < 2; ++s) {
    const int arow = i0 + wid * 32 + s * 16 + n;
    a0[s] = *(const bf16x8*)&A[(size_t)arow * DM + quad * 8];
    a1[s] = *(const bf16x8*)&A[(size_t)arow * DM + 32 + quad * 8];
#pragma unroll
    for (int r = 0; r < 4; ++r) na[s][r] = nA[i0 + wid * 32 + s * 16 + quad * 4 + r];
  }
  bf16x8 b0[8], b1[8];
  float nb[8];
#pragma unroll
  for (int nt = 0; nt < 8; ++nt) {
    const int brow = j0 + nt * 16 + n;
    b0[nt] = *(const bf16x8*)&B[(size_t)brow * DM + quad * 8];
    b1[nt] = *(const bf16x8*)&B[(size_t)brow * DM + 32 + quad * 8];
    nb[nt] = nB[j0 + nt * 16 + n];
  }

  float local = 0.f;
#pragma unroll
  for (int nt = 0; nt < 8; ++nt) {
#pragma unroll
    for (int s = 0; s < 2; ++s) {
      f32x4 zf = {0.f, 0.f, 0.f, 0.f};
      f32x4 d4 = __builtin_amdgcn_mfma_f32_16x16x32_bf16(a0[s], b0[nt], zf, 0, 0, 0);
      d4 = __builtin_amdgcn_mfma_f32_16x16x32_bf16(a1[s], b1[nt], d4, 0, 0, 0);
#pragma unroll
      for (int r = 0; r < 4; ++r) {
        float dist = na[s][r] + nb[nt] - 2.0f * d4[r];
        local += EXP2(MMDC * dist);
      }
    }
  }

  float tot = wave_sum64(local);
  __shared__ float wpart[4];
  if (lane == 0) wpart[wid] = tot;
  __syncthreads();
  if (tid == 0)
    partials[bid] = coef * (wpart[0] + wpart[1] + wpart[2] + wpart[3]);
}

// ---------------------------------------------------------------- reduce + finalize (1 block)
__global__ __launch_bounds__(256) void reducefin_kernel(const float* __restrict__ partials,
                                                        float* __restrict__ out) {
  const int tid = threadIdx.x;
  float s = 0.f;
  for (int i = tid; i < 2080; i += 256) s += partials[i];
  s = wave_sum64(s);
  __shared__ float L[4];
  if ((tid & 63) == 0) L[tid >> 6] = s;
  __syncthreads();
  if (tid == 0) {
    const float invn = 1.0f / ((float)MT * (float)MT);
    out[(size_t)MT * DM] = (L[0] + L[1] + L[2] + L[3]) * invn;
  }
}

// ================================================================ launcher
extern "C" void kernel_launch(void* const* d_in, const int* in_sizes, int n_in,
                              void* d_out, int out_size, void* d_ws, size_t ws_size,
                              hipStream_t stream) {
  const float* hsi  = (const float*)d_in[0];
  const float* rgb  = (const float*)d_in[1];
  const float* inw  = (const float*)d_in[2];
  const float* inb  = (const float*)d_in[3];
  const float* ow   = (const float*)d_in[4];
  const float* obv  = (const float*)d_in[5];
  const float* l1w  = (const float*)d_in[6];
  const float* l1b  = (const float*)d_in[7];
  const float* l2w  = (const float*)d_in[8];
  const float* l2b  = (const float*)d_in[9];
  const float* n1w  = (const float*)d_in[10];
  const float* n1b  = (const float*)d_in[11];
  const float* n2w  = (const float*)d_in[12];
  const float* n2b  = (const float*)d_in[13];
  const float* mask = (const float*)d_in[14];
  float* out = (float*)d_out;

  float* ws      = (float*)d_ws;
  float* x       = ws;                          // 262144
  short* pbufb   = (short*)(ws + 262144);       // 8 z * MT*64 shorts = 1048576 floats
  float* lbuf    = ws + 1310720;                // 8 * 32768 = 262144
  float* nrm     = ws + 1572864;                // 8192
  float* parts   = ws + 1581056;                // 4096
  float* Wti     = ws + 1585152;                // 49152 (packed)
  float* Wto     = ws + 1634304;                // 16384
  float* Wt1     = ws + 1650688;                // 65536
  float* Wt2     = ws + 1716224;                // 65536
  short* xmb     = (short*)(ws + 1781760);      // 262144 shorts
  short* rgbb    = (short*)(ws + 1912832);      // 262144 shorts
  _Float16* Qh   = (_Float16*)(ws + 2043904);   // 262144 f16
  _Float16* Kh   = (_Float16*)(ws + 2174976);   // 262144 f16
  short* Vtb     = (short*)(ws + 2306048);      // 262144 shorts

  prep_kernel<<<192 + MT / 4 + MT / 4, 256, 0, stream>>>(
      inw, Wti, ow, Wto, l1w, Wt1, l2w, Wt2, rgb, rgbb, nrm,
      hsi, inb, x, Qh, Kh, Vtb);

  for (int i = 0; i < NLAYER; ++i) {
    attn_kernel<<<dim3(MT / 128, NHEAD, ZSPLIT), 256, 0, stream>>>(Qh, Kh, Vtb, pbufb, lbuf);
    const int last = (i == NLAYER - 1);
    dense_kernel<<<MT / 8, 512, 0, stream>>>(
        pbufb, lbuf, x,
        Wto + (size_t)i * DM * DM, obv + (size_t)i * DM,
        n1w + (size_t)i * DM, n1b + (size_t)i * DM,
        Wt1 + (size_t)i * DFF * DM, l1b + (size_t)i * DFF,
        Wt2 + (size_t)i * DM * DFF, l2b + (size_t)i * DM,
        n2w + (size_t)i * DM, n2b + (size_t)i * DM,
        Wti + (size_t)(last ? 0 : (i + 1)) * 192 * DM,
        inb + (size_t)(last ? 0 : (i + 1)) * 192,
        Qh, Kh, Vtb, !last,
        mask, out, xmb, nrm, last);
  }

  mmd_kernel<<<2080, 256, 0, stream>>>(xmb, rgbb, nrm, parts);
  reducefin_kernel<<<1, 256, 0, stream>>>(parts, out);
}